// Round 14
// baseline (357.928 us; speedup 1.0000x reference)
//
#include <hip/hip_runtime.h>
#include <hip/hip_fp16.h>

#define NN 20000      // nodes
#define NE 320000     // edges
#define SS 2          // feature axis
#define FIN 128
#define FH 246
#define MPAD 40064    // M (=NN*SS) padded to 64

typedef _Float16 f16x8 __attribute__((ext_vector_type(8)));
typedef float f32x4 __attribute__((ext_vector_type(4)));

// ---------------- MERGED SETUP (r29): degree + W pre-split + init_out + zero_pads ----
__global__ void setup_kernel(const int* __restrict__ src, const int* __restrict__ dst,
                             int* __restrict__ deg_out, int* __restrict__ deg_in,
                             const float* __restrict__ W0, const float* __restrict__ W1,
                             const float* __restrict__ W2,
                             ushort* __restrict__ Wh0, ushort* __restrict__ Wl0,
                             ushort* __restrict__ Wh1, ushort* __restrict__ Wl1,
                             ushort* __restrict__ Wh2, ushort* __restrict__ Wl2,
                             float* __restrict__ out, const float* __restrict__ fcb,
                             float* __restrict__ norm_out,
                             ushort* __restrict__ Ah, ushort* __restrict__ Al,
                             float* __restrict__ bufH) {
    int blk = blockIdx.x, tid = threadIdx.x;
    if (blk < 1250) {                       // ---- degree histogram
        int e = blk * 256 + tid;
        if (e < NE) {
            atomicAdd(&deg_out[src[e]], 1);
            atomicAdd(&deg_in[dst[e]], 1);
        }
    } else if (blk < 2018) {                // ---- W pre-split, FRAG-PACKED
        int idx = blk - 1250;
        int n = idx & 255, layer = idx >> 8, k = tid;
        const float* W; ushort* Wh; ushort* Wl; int K;
        if (layer == 0)      { W = W0; Wh = Wh0; Wl = Wl0; K = FIN; }
        else if (layer == 1) { W = W1; Wh = Wh1; Wl = Wl1; K = FH; }
        else                 { W = W2; Wh = Wh2; Wl = Wl2; K = FH; }
        float v = (k < K && n < 246) ? W[k * 246 + n] : 0.f;
        _Float16 h = (_Float16)v;
        _Float16 l = (_Float16)(v - (float)h);
        int c16 = n >> 4, lr = n & 15, kt = k >> 5, quad = (k >> 3) & 3, j = k & 7;
        int off = ((c16 * 8 + kt) * 64 + quad * 16 + lr) * 8 + j;
        Wh[off] = *(ushort*)&h;
        Wl[off] = *(ushort*)&l;
    } else if (blk < 2097) {                // ---- init_out
        int i = (blk - 2018) * 256 + tid;
        if (i < NN) out[i] = fcb[0];
        if (i == 0) norm_out[NN] = 0.f;     // dead-norm entry for layer-0 pad edges
    } else {                                // ---- zero pads
        int i = (blk - 2097) * 256 + tid;   // [0, 4352)
        if (i < 4096) {                     // panel pads: kt<8, m in [40000,40064)
            int kt = i >> 9, r = i & 511;
            int m = NN * SS + (r >> 3), j = r & 7;
            size_t o = ((size_t)kt * MPAD + m) * 8 + j;
            ((unsigned long long*)Ah)[o] = 0ull;
            ((unsigned long long*)Al)[o] = 0ull;
        } else {                            // bufH pad row (node NN): 512 floats
            int j = i - 4096;               // 256 ull
            ((unsigned long long*)(bufH + (size_t)NN * 512))[j] = 0ull;
        }
    }
}

// ---------------- norms + parallel CSR range allocation (fused) ----------------
__global__ void alloc_kernel(const int* __restrict__ deg_out, const int* __restrict__ deg_in,
                             float* __restrict__ norm_out, float* __restrict__ norm_in,
                             int* __restrict__ row_start, int* __restrict__ cursor,
                             int* __restrict__ counter) {
    __shared__ int smem[256];
    __shared__ int base_s;
    int tid = threadIdx.x;
    int i = blockIdx.x * 256 + tid;
    int v  = (i < NN) ? deg_in[i] : 0;
    int vp = (v + 3) & ~3;                 // padded degree
    smem[tid] = vp;
    __syncthreads();
    for (int off = 1; off < 256; off <<= 1) {
        int t = (tid >= off) ? smem[tid - off] : 0;
        __syncthreads();
        smem[tid] += t;
        __syncthreads();
    }
    int incl = smem[tid];
    if (tid == 0) base_s = atomicAdd(counter, smem[255]);
    __syncthreads();
    if (i < NN) {
        int excl = base_s + incl - vp;     // multiple of 4 by construction
        row_start[i] = excl;
        cursor[i]    = excl;
        norm_out[i] = rsqrtf(fmaxf((float)deg_out[i], 1.0f));
        norm_in[i]  = rsqrtf(fmaxf((float)v, 1.0f));
    }
}

// ---------------- MERGED scatter + pad_fill (r29) ----------------
__global__ void scatter_pad(const int* __restrict__ src, const int* __restrict__ dst,
                            int* __restrict__ cursor, ushort* __restrict__ sorted_src,
                            const int* __restrict__ row_start, const int* __restrict__ deg_in) {
    int blk = blockIdx.x, tid = threadIdx.x;
    if (blk < 1250) {
        int e = blk * 256 + tid;
        if (e < NE) {
            int d = dst[e];
            int pos = atomicAdd(&cursor[d], 1);
            sorted_src[pos] = (ushort)src[e];
        }
    } else {
        int n = (blk - 1250) * 256 + tid;
        if (n < NN) {
            int d = deg_in[n];
            int beg = row_start[n] + d;
            int end = row_start[n] + ((d + 3) & ~3);
            for (int p = beg; p < end; ++p) sorted_src[p] = (ushort)NN;
        }
    }
}

// ---------------- XCD-pinned chunk-tiled gather-aggregate, split-f16 output ----------
// r24-proven geometry: 16 lanes/node, 256B chunks, 4 nodes/wave, XCD chunk
// pinning (r28 removed it -> FETCH 118->293MB, 51->92us: locality IS the
// mechanism). Regular stores (NT pushed A to HBM, r23). Pure segment-sum
// (norms folded into producer); ushort4 packed indices, ranges 4-padded
// (pad src=NN -> zero row). NORM=true only layer 0.
template<int F4ROW, int NCH, bool NORM>
__global__ void aggregate4(const float* __restrict__ h,
                           const int* __restrict__ row_start,
                           const int* __restrict__ deg_in,
                           const ushort* __restrict__ sorted_src,
                           const float* __restrict__ norm_out,
                           const float* __restrict__ norm_in,
                           ushort* __restrict__ Ah, ushort* __restrict__ Al) {
    constexpr int IHALF = F4ROW / 2;
    int g  = threadIdx.x >> 4;              // 0..7: node sub-index
    int l  = threadIdx.x & 15;              // float4 within chunk
    int cb = blockIdx.x & (NCH - 1);        // chunk (XCD-pinned axis)
    int nb = blockIdx.x / NCH;              // node group
    int n  = nb * 8 + g;
    if (n >= NN) return;
    int idx = cb * 16 + l;                  // < F4ROW (= NCH*16)
    const float4* hv = (const float4*)h;
    int beg = row_start[n];
    int end = beg + ((deg_in[n] + 3) & ~3);
    float4 acc = {0.f, 0.f, 0.f, 0.f};
    ushort4 ss;
    if (beg < end) ss = *(const ushort4*)&sorted_src[beg];   // 8B aligned (beg%4==0)
    for (int i = beg; i < end; i += 4) {
        ushort4 cur = ss;
        if (i + 4 < end) ss = *(const ushort4*)&sorted_src[i + 4];   // prefetch
        int s0 = cur.x, s1 = cur.y, s2 = cur.z, s3 = cur.w;
        if (NORM) {
            float n0 = norm_out[s0], n1 = norm_out[s1];
            float n2 = norm_out[s2], n3 = norm_out[s3];
            float4 v0 = hv[(size_t)(s0 < NN ? s0 : NN - 1) * F4ROW + idx];
            float4 v1 = hv[(size_t)(s1 < NN ? s1 : NN - 1) * F4ROW + idx];
            float4 v2 = hv[(size_t)(s2 < NN ? s2 : NN - 1) * F4ROW + idx];
            float4 v3 = hv[(size_t)(s3 < NN ? s3 : NN - 1) * F4ROW + idx];
            acc.x += v0.x * n0 + v1.x * n1 + v2.x * n2 + v3.x * n3;
            acc.y += v0.y * n0 + v1.y * n1 + v2.y * n2 + v3.y * n3;
            acc.z += v0.z * n0 + v1.z * n1 + v2.z * n2 + v3.z * n3;
            acc.w += v0.w * n0 + v1.w * n1 + v2.w * n2 + v3.w * n3;
        } else {
            float4 v0 = hv[(size_t)s0 * F4ROW + idx];   // s=NN -> zeroed pad row
            float4 v1 = hv[(size_t)s1 * F4ROW + idx];
            float4 v2 = hv[(size_t)s2 * F4ROW + idx];
            float4 v3 = hv[(size_t)s3 * F4ROW + idx];
            acc.x += v0.x + v1.x + v2.x + v3.x;
            acc.y += v0.y + v1.y + v2.y + v3.y;
            acc.z += v0.z + v1.z + v2.z + v3.z;
            acc.w += v0.w + v1.w + v2.w + v3.w;
        }
    }
    float ni = norm_in[n];
    float v[4] = {acc.x * ni, acc.y * ni, acc.z * ni, acc.w * ni};
    ushort hp[4], lp[4];
#pragma unroll
    for (int j = 0; j < 4; ++j) {
        _Float16 hh = (_Float16)v[j];
        _Float16 ll = (_Float16)(v[j] - (float)hh);
        hp[j] = *(ushort*)&hh;
        lp[j] = *(ushort*)&ll;
    }
    // K-tiled panel store (regular stores -> stays L2-resident for the GEMM)
    int s  = (idx >= IHALF);
    int ik = idx & (IHALF - 1);
    size_t o = ((size_t)(ik >> 3) * MPAD + n * 2 + s) * 8 + (ik & 7);
    ((unsigned long long*)Ah)[o] = *(unsigned long long*)hp;
    ((unsigned long long*)Al)[o] = *(unsigned long long*)lp;
}

// ---------------- split-f16 MFMA GEMM, SGB-pinned 2-deep pipeline (r30) ----------
// r23 counter decode: MfmaUtil 10.1% == 72 MFMA x 5cy / (360 + 8x~300cy exposed
// latency) -- the compiler SINKS each global load to just before its use (chose
// VGPR=60 when 512 were allowed), so every source-level "pipeline" compiled to
// the same serial load->wait->MFMA chain (7 structures, all 50-56us). r30 pins
// the schedule with sched_group_barrier: per K-step, issue ALL 16 VMEM reads
// (buffers for t+1), THEN 72 MFMA (step t) -- the MFMAs (~360cy) cover the L2
// latency of the prefetch. Masks (m137): VMEM_READ=0x20, MFMA=0x8.
// NO LDS, NO barriers. Wave tile 32M x 64N (block 64M x 128N, 4 waves 2x2).
// acc += Ah*Wh + Al*Wh + Ah*Wl.
// FUSE: relu -> *fc_w -> mean_s -> 16-lane reduce -> atomicAdd(out[node], 0.5p).
#define LOAD_A(T, AH, AL)                                                        \
    _Pragma("unroll")                                                            \
    for (int mi = 0; mi < 2; ++mi) {                                             \
        size_t fh = ((size_t)(T) * MPAD + m0 + wm * 32 + mi * 16 + lr) * 32 + quad * 8; \
        AH[mi] = *(const f16x8*)(Ah + fh);                                       \
        AL[mi] = *(const f16x8*)(Al + fh);                                       \
    }
#define LOAD_B(T, BH, BL)                                                        \
    _Pragma("unroll")                                                            \
    for (int ni = 0; ni < 4; ++ni) {                                             \
        size_t o = ((size_t)((c0 + ni) * 8 + (T)) * 64 + lane) * 8;              \
        BH[ni] = *(const f16x8*)(Whp + o);                                       \
        BL[ni] = *(const f16x8*)(Wlp + o);                                       \
    }
#define DO_MFMA(AH, AL, BH, BL)                                                  \
    _Pragma("unroll")                                                            \
    for (int mi = 0; mi < 2; ++mi)                                               \
        _Pragma("unroll")                                                        \
        for (int ni = 0; ni < 4; ++ni) {                                         \
            acc[mi][ni] = __builtin_amdgcn_mfma_f32_16x16x32_f16(AH[mi], BH[ni], acc[mi][ni], 0, 0, 0); \
            acc[mi][ni] = __builtin_amdgcn_mfma_f32_16x16x32_f16(AL[mi], BH[ni], acc[mi][ni], 0, 0, 0); \
            acc[mi][ni] = __builtin_amdgcn_mfma_f32_16x16x32_f16(AH[mi], BL[ni], acc[mi][ni], 0, 0, 0); \
        }

template<int KP, bool FUSE>
__global__ __launch_bounds__(256, 2) void gemm_pipe(const ushort* __restrict__ Ah,
                                                    const ushort* __restrict__ Al,
                                                    const ushort* __restrict__ Whp,
                                                    const ushort* __restrict__ Wlp,
                                                    const float* __restrict__ b,
                                                    void* __restrict__ outv,
                                                    const float* __restrict__ fcw,
                                                    const float* __restrict__ nrm) {
    constexpr int NT = KP / 32;
    int tid  = threadIdx.x;
    int m0   = blockIdx.x * 64;
    int n0   = blockIdx.y * 128;
    int wave = tid >> 6, lane = tid & 63;
    int wm = wave >> 1, wn = wave & 1;
    int lr = lane & 15, quad = lane >> 4;
    int c0 = (n0 + wn * 64) >> 4;          // first 16-col tile index

    f32x4 acc[2][4];
#pragma unroll
    for (int mi = 0; mi < 2; ++mi)
#pragma unroll
        for (int ni = 0; ni < 4; ++ni) acc[mi][ni] = {0.f, 0.f, 0.f, 0.f};

    f16x8 a0h[2], a0l[2], b0h[4], b0l[4];
    f16x8 a1h[2], a1l[2], b1h[4], b1l[4];
    LOAD_A(0, a0h, a0l)
    LOAD_B(0, b0h, b0l)
#pragma unroll
    for (int t = 0; t < NT; ++t) {
        if (t & 1) {
            if (t + 1 < NT) { LOAD_A(t + 1, a0h, a0l) LOAD_B(t + 1, b0h, b0l) }
            DO_MFMA(a1h, a1l, b1h, b1l)
        } else {
            if (t + 1 < NT) { LOAD_A(t + 1, a1h, a1l) LOAD_B(t + 1, b1h, b1l) }
            DO_MFMA(a0h, a0l, b0h, b0l)
        }
        // ---- pin the schedule: 16 VMEM reads (prefetch t+1) THEN 72 MFMA (t)
        if (t + 1 < NT) {
            __builtin_amdgcn_sched_group_barrier(0x20, 16, 0);  // VMEM_READ
            __builtin_amdgcn_sched_group_barrier(0x8, 72, 0);   // MFMA
        } else {
            __builtin_amdgcn_sched_group_barrier(0x8, 72, 0);   // last step: MFMA only
        }
    }

    if (FUSE) {
        float* out = (float*)outv;
#pragma unroll
        for (int mi = 0; mi < 2; ++mi) {
#pragma unroll
            for (int i = 0; i < 4; ++i) {
                float p = 0.f;
#pragma unroll
                for (int ni = 0; ni < 4; ++ni) {
                    int c = n0 + wn * 64 + ni * 16 + lr;
                    if (c < 246)
                        p += fmaxf(acc[mi][ni][i] + b[c], 0.f) * fcw[c];
                }
#pragma unroll
                for (int off = 8; off > 0; off >>= 1)
                    p += __shfl_down(p, off, 16);
                int m = m0 + wm * 32 + mi * 16 + quad * 4 + i;
                if (lr == 0 && m < NN * SS)
                    atomicAdd(&out[m >> 1], 0.5f * p);
            }
        }
    } else {
        float* outF = (float*)outv;    // fp32 [M][256]; cols>=246 get 0 (acc=0, bj=0)
#pragma unroll
        for (int ni = 0; ni < 4; ++ni) {
            int c = n0 + wn * 64 + ni * 16 + lr;
            float bj = (c < 246) ? b[c] : 0.f;
#pragma unroll
            for (int mi = 0; mi < 2; ++mi)
#pragma unroll
                for (int i = 0; i < 4; ++i) {
                    int m = m0 + wm * 32 + mi * 16 + quad * 4 + i;
                    if (m < NN * SS) {
                        float no = nrm[m >> 1];
                        outF[(size_t)m * 256 + c] = fmaxf(acc[mi][ni][i] + bj, 0.f) * no;
                    }
                }
        }
    }
}

extern "C" void kernel_launch(void* const* d_in, const int* in_sizes, int n_in,
                              void* d_out, int out_size, void* d_ws, size_t ws_size,
                              hipStream_t stream) {
    const float* feat = (const float*)d_in[0];
    const int*   src  = (const int*)d_in[1];
    const int*   dst  = (const int*)d_in[2];
    const float* W0   = (const float*)d_in[3];
    const float* b0   = (const float*)d_in[4];
    const float* W1   = (const float*)d_in[5];
    const float* b1   = (const float*)d_in[6];
    const float* W2   = (const float*)d_in[7];
    const float* b2   = (const float*)d_in[8];
    const float* fcw  = (const float*)d_in[9];
    const float* fcb  = (const float*)d_in[10];
    float* out = (float*)d_out;

    char* ws = (char*)d_ws;
    size_t off = 0;
    auto alloc = [&](size_t bytes) {
        void* p = ws + off;
        off = (off + bytes + 255) & ~(size_t)255;
        return p;
    };
    int*    deg_out_i = (int*)alloc((2 * NN + 64) * sizeof(int));
    int*    deg_in_i  = deg_out_i + NN;
    int*    counter   = deg_out_i + 2 * NN;
    int*    row_start = (int*)alloc(NN * sizeof(int));
    int*    cursor    = (int*)alloc(NN * sizeof(int));
    ushort* sorted    = (ushort*)alloc((NE + 3 * NN + 16) * sizeof(ushort));
    float*  norm_out  = (float*)alloc((NN + 1) * sizeof(float));   // [NN] = 0 (pad)
    float*  norm_in   = (float*)alloc(NN * sizeof(float));
    ushort* Wh0 = (ushort*)alloc(256 * 256 * sizeof(ushort));
    ushort* Wl0 = (ushort*)alloc(256 * 256 * sizeof(ushort));
    ushort* Wh1 = (ushort*)alloc(256 * 256 * sizeof(ushort));
    ushort* Wl1 = (ushort*)alloc(256 * 256 * sizeof(ushort));
    ushort* Wh2 = (ushort*)alloc(256 * 256 * sizeof(ushort));
    ushort* Wl2 = (ushort*)alloc(256 * 256 * sizeof(ushort));
    ushort* Ahb = (ushort*)alloc((size_t)MPAD * 256 * sizeof(ushort));  // split A hi (K-tiled)
    ushort* Alb = (ushort*)alloc((size_t)MPAD * 256 * sizeof(ushort));  // split A lo (K-tiled)
    float*  bufH = (float*)alloc(((size_t)NN * SS * 256 + 512) * sizeof(float)); // +zero pad row

    hipMemsetAsync(deg_out_i, 0, (2 * NN + 1) * sizeof(int), stream);

    // K1: all independent setup (degree + W-split + init_out + pad zeroing)
    setup_kernel<<<2114, 256, 0, stream>>>(src, dst, deg_out_i, deg_in_i,
                                           W0, W1, W2, Wh0, Wl0, Wh1, Wl1, Wh2, Wl2,
                                           out, fcb, norm_out, Ahb, Alb, bufH);
    // K2: CSR ranges + norms (needs degree)
    alloc_kernel<<<(NN + 255) / 256, 256, 0, stream>>>(deg_out_i, deg_in_i, norm_out, norm_in,
                                                       row_start, cursor, counter);
    // K3: scatter + pad_fill (needs alloc)
    scatter_pad<<<1250 + (NN + 255) / 256, 256, 0, stream>>>(src, dst, cursor, sorted,
                                                             row_start, deg_in_i);

    const int NB8 = (NN + 7) / 8;             // 2500 node groups (8 nodes/block)
    dim3 ggrid(MPAD / 64, 2);                 // 626 x 2 = 1252 blocks

    // Layer 0: feat [N][2*128] -> agg (norm gathers, row clamp) -> gemm(*norm_out) -> bufH
    aggregate4<64, 4, true><<<NB8 * 4, 128, 0, stream>>>(feat, row_start, deg_in_i, sorted,
                                                         norm_out, norm_in, Ahb, Alb);
    gemm_pipe<FIN, false><<<ggrid, 256, 0, stream>>>(Ahb, Alb, Wh0, Wl0, b0, bufH, fcw, norm_out);

    // Layer 1: bufH (pre-scaled by norm_out) -> pure-sum agg -> gemm(*norm_out) -> bufH
    aggregate4<128, 8, false><<<NB8 * 8, 128, 0, stream>>>(bufH, row_start, deg_in_i, sorted,
                                                           norm_out, norm_in, Ahb, Alb);
    gemm_pipe<256, false><<<ggrid, 256, 0, stream>>>(Ahb, Alb, Wh1, Wl1, b1, bufH, fcw, norm_out);

    // Layer 2: bufH -> pure-sum agg -> fused gemm -> out (atomicAdd; out pre-set to fcb)
    aggregate4<128, 8, false><<<NB8 * 8, 128, 0, stream>>>(bufH, row_start, deg_in_i, sorted,
                                                           norm_out, norm_in, Ahb, Alb);
    gemm_pipe<256, true><<<ggrid, 256, 0, stream>>>(Ahb, Alb, Wh2, Wl2, b2, out, fcw, norm_out);
}

// Round 15
// 339.719 us; speedup vs baseline: 1.0536x; 1.0536x over previous
//
#include <hip/hip_runtime.h>
#include <hip/hip_fp16.h>

#define NN 20000      // nodes
#define NE 320000     // edges
#define SS 2          // feature axis
#define FIN 128
#define FH 246
#define MPAD 40064    // M (=NN*SS) padded to 64

typedef _Float16 f16x8 __attribute__((ext_vector_type(8)));
typedef float f32x4 __attribute__((ext_vector_type(4)));

// ---------------- MERGED SETUP (r29): degree + W pre-split + init_out + zero_pads ----
__global__ void setup_kernel(const int* __restrict__ src, const int* __restrict__ dst,
                             int* __restrict__ deg_out, int* __restrict__ deg_in,
                             const float* __restrict__ W0, const float* __restrict__ W1,
                             const float* __restrict__ W2,
                             ushort* __restrict__ Wh0, ushort* __restrict__ Wl0,
                             ushort* __restrict__ Wh1, ushort* __restrict__ Wl1,
                             ushort* __restrict__ Wh2, ushort* __restrict__ Wl2,
                             float* __restrict__ out, const float* __restrict__ fcb,
                             float* __restrict__ norm_out,
                             ushort* __restrict__ Ah, ushort* __restrict__ Al,
                             float* __restrict__ bufH) {
    int blk = blockIdx.x, tid = threadIdx.x;
    if (blk < 1250) {                       // ---- degree histogram
        int e = blk * 256 + tid;
        if (e < NE) {
            atomicAdd(&deg_out[src[e]], 1);
            atomicAdd(&deg_in[dst[e]], 1);
        }
    } else if (blk < 2018) {                // ---- W pre-split, FRAG-PACKED
        int idx = blk - 1250;
        int n = idx & 255, layer = idx >> 8, k = tid;
        const float* W; ushort* Wh; ushort* Wl; int K;
        if (layer == 0)      { W = W0; Wh = Wh0; Wl = Wl0; K = FIN; }
        else if (layer == 1) { W = W1; Wh = Wh1; Wl = Wl1; K = FH; }
        else                 { W = W2; Wh = Wh2; Wl = Wl2; K = FH; }
        float v = (k < K && n < 246) ? W[k * 246 + n] : 0.f;
        _Float16 h = (_Float16)v;
        _Float16 l = (_Float16)(v - (float)h);
        int c16 = n >> 4, lr = n & 15, kt = k >> 5, quad = (k >> 3) & 3, j = k & 7;
        int off = ((c16 * 8 + kt) * 64 + quad * 16 + lr) * 8 + j;
        Wh[off] = *(ushort*)&h;
        Wl[off] = *(ushort*)&l;
    } else if (blk < 2097) {                // ---- init_out
        int i = (blk - 2018) * 256 + tid;
        if (i < NN) out[i] = fcb[0];
        if (i == 0) norm_out[NN] = 0.f;     // dead-norm entry for layer-0 pad edges
    } else {                                // ---- zero pads
        int i = (blk - 2097) * 256 + tid;   // [0, 4352)
        if (i < 4096) {                     // panel pads: kt<8, m in [40000,40064)
            int kt = i >> 9, r = i & 511;
            int m = NN * SS + (r >> 3), j = r & 7;
            size_t o = ((size_t)kt * MPAD + m) * 8 + j;
            ((unsigned long long*)Ah)[o] = 0ull;
            ((unsigned long long*)Al)[o] = 0ull;
        } else {                            // bufH pad row (node NN): 512 floats
            int j = i - 4096;               // 256 ull
            ((unsigned long long*)(bufH + (size_t)NN * 512))[j] = 0ull;
        }
    }
}

// ---------------- norms + parallel CSR range allocation (fused) ----------------
__global__ void alloc_kernel(const int* __restrict__ deg_out, const int* __restrict__ deg_in,
                             float* __restrict__ norm_out, float* __restrict__ norm_in,
                             int* __restrict__ row_start, int* __restrict__ cursor,
                             int* __restrict__ counter) {
    __shared__ int smem[256];
    __shared__ int base_s;
    int tid = threadIdx.x;
    int i = blockIdx.x * 256 + tid;
    int v  = (i < NN) ? deg_in[i] : 0;
    int vp = (v + 3) & ~3;                 // padded degree
    smem[tid] = vp;
    __syncthreads();
    for (int off = 1; off < 256; off <<= 1) {
        int t = (tid >= off) ? smem[tid - off] : 0;
        __syncthreads();
        smem[tid] += t;
        __syncthreads();
    }
    int incl = smem[tid];
    if (tid == 0) base_s = atomicAdd(counter, smem[255]);
    __syncthreads();
    if (i < NN) {
        int excl = base_s + incl - vp;     // multiple of 4 by construction
        row_start[i] = excl;
        cursor[i]    = excl;
        norm_out[i] = rsqrtf(fmaxf((float)deg_out[i], 1.0f));
        norm_in[i]  = rsqrtf(fmaxf((float)v, 1.0f));
    }
}

// ---------------- MERGED scatter + pad_fill (r29) ----------------
__global__ void scatter_pad(const int* __restrict__ src, const int* __restrict__ dst,
                            int* __restrict__ cursor, ushort* __restrict__ sorted_src,
                            const int* __restrict__ row_start, const int* __restrict__ deg_in) {
    int blk = blockIdx.x, tid = threadIdx.x;
    if (blk < 1250) {
        int e = blk * 256 + tid;
        if (e < NE) {
            int d = dst[e];
            int pos = atomicAdd(&cursor[d], 1);
            sorted_src[pos] = (ushort)src[e];
        }
    } else {
        int n = (blk - 1250) * 256 + tid;
        if (n < NN) {
            int d = deg_in[n];
            int beg = row_start[n] + d;
            int end = row_start[n] + ((d + 3) & ~3);
            for (int p = beg; p < end; ++p) sorted_src[p] = (ushort)NN;
        }
    }
}

// ---------------- XCD-pinned chunk-tiled gather-aggregate, split-f16 output ----------
// r24-proven geometry: 16 lanes/node, 256B chunks, 4 nodes/wave, XCD chunk
// pinning (r28 removed it -> FETCH 118->293MB, 51->92us: locality IS the
// mechanism). Regular stores (NT pushed A to HBM, r23). Pure segment-sum
// (norms folded into producer); ushort4 packed indices, ranges 4-padded
// (pad src=NN -> zero row). NORM=true only layer 0.
template<int F4ROW, int NCH, bool NORM>
__global__ void aggregate4(const float* __restrict__ h,
                           const int* __restrict__ row_start,
                           const int* __restrict__ deg_in,
                           const ushort* __restrict__ sorted_src,
                           const float* __restrict__ norm_out,
                           const float* __restrict__ norm_in,
                           ushort* __restrict__ Ah, ushort* __restrict__ Al) {
    constexpr int IHALF = F4ROW / 2;
    int g  = threadIdx.x >> 4;              // 0..7: node sub-index
    int l  = threadIdx.x & 15;              // float4 within chunk
    int cb = blockIdx.x & (NCH - 1);        // chunk (XCD-pinned axis)
    int nb = blockIdx.x / NCH;              // node group
    int n  = nb * 8 + g;
    if (n >= NN) return;
    int idx = cb * 16 + l;                  // < F4ROW (= NCH*16)
    const float4* hv = (const float4*)h;
    int beg = row_start[n];
    int end = beg + ((deg_in[n] + 3) & ~3);
    float4 acc = {0.f, 0.f, 0.f, 0.f};
    ushort4 ss;
    if (beg < end) ss = *(const ushort4*)&sorted_src[beg];   // 8B aligned (beg%4==0)
    for (int i = beg; i < end; i += 4) {
        ushort4 cur = ss;
        if (i + 4 < end) ss = *(const ushort4*)&sorted_src[i + 4];   // prefetch
        int s0 = cur.x, s1 = cur.y, s2 = cur.z, s3 = cur.w;
        if (NORM) {
            float n0 = norm_out[s0], n1 = norm_out[s1];
            float n2 = norm_out[s2], n3 = norm_out[s3];
            float4 v0 = hv[(size_t)(s0 < NN ? s0 : NN - 1) * F4ROW + idx];
            float4 v1 = hv[(size_t)(s1 < NN ? s1 : NN - 1) * F4ROW + idx];
            float4 v2 = hv[(size_t)(s2 < NN ? s2 : NN - 1) * F4ROW + idx];
            float4 v3 = hv[(size_t)(s3 < NN ? s3 : NN - 1) * F4ROW + idx];
            acc.x += v0.x * n0 + v1.x * n1 + v2.x * n2 + v3.x * n3;
            acc.y += v0.y * n0 + v1.y * n1 + v2.y * n2 + v3.y * n3;
            acc.z += v0.z * n0 + v1.z * n1 + v2.z * n2 + v3.z * n3;
            acc.w += v0.w * n0 + v1.w * n1 + v2.w * n2 + v3.w * n3;
        } else {
            float4 v0 = hv[(size_t)s0 * F4ROW + idx];   // s=NN -> zeroed pad row
            float4 v1 = hv[(size_t)s1 * F4ROW + idx];
            float4 v2 = hv[(size_t)s2 * F4ROW + idx];
            float4 v3 = hv[(size_t)s3 * F4ROW + idx];
            acc.x += v0.x + v1.x + v2.x + v3.x;
            acc.y += v0.y + v1.y + v2.y + v3.y;
            acc.z += v0.z + v1.z + v2.z + v3.z;
            acc.w += v0.w + v1.w + v2.w + v3.w;
        }
    }
    float ni = norm_in[n];
    float v[4] = {acc.x * ni, acc.y * ni, acc.z * ni, acc.w * ni};
    ushort hp[4], lp[4];
#pragma unroll
    for (int j = 0; j < 4; ++j) {
        _Float16 hh = (_Float16)v[j];
        _Float16 ll = (_Float16)(v[j] - (float)hh);
        hp[j] = *(ushort*)&hh;
        lp[j] = *(ushort*)&lp[j];
        lp[j] = *(ushort*)&ll;
    }
    // K-tiled panel store (regular stores -> stays L2-resident for the GEMM)
    int s  = (idx >= IHALF);
    int ik = idx & (IHALF - 1);
    size_t o = ((size_t)(ik >> 3) * MPAD + n * 2 + s) * 8 + (ik & 7);
    ((unsigned long long*)Ah)[o] = *(unsigned long long*)hp;
    ((unsigned long long*)Al)[o] = *(unsigned long long*)lp;
}

// ---------------- split-f16 MFMA GEMM, 2-deep pipeline + XCD tile swizzle (r31) ----
// r24 structure (345.8us best; SGB r30 regressed -> reverted). r31: the A-panel
// K-tiles are written XCD-pinned by the aggregate, so the default round-robin
// GEMM grid read ~3/4 of A cross-XCD (L3 ~500cy) -- FETCH == |A|, zero L2
// reuse. Fix: 1D grid + bijective chunked swizzle (m204): each XCD gets a
// contiguous tile run with (by=0, by=1) column-pairs adjacent -> the pair's
// second A-strip read hits own-XCD L2 (2x A reuse).
// NO LDS, NO barriers; 2-deep static double-buffer. Wave tile 32M x 64N
// (block 64M x 128N, 4 waves 2x2). acc += Ah*Wh + Al*Wh + Ah*Wl.
// FUSE: relu -> *fc_w -> mean_s -> 16-lane reduce -> atomicAdd(out[node], 0.5p).
#define LOAD_A(T, AH, AL)                                                        \
    _Pragma("unroll")                                                            \
    for (int mi = 0; mi < 2; ++mi) {                                             \
        size_t fh = ((size_t)(T) * MPAD + m0 + wm * 32 + mi * 16 + lr) * 32 + quad * 8; \
        AH[mi] = *(const f16x8*)(Ah + fh);                                       \
        AL[mi] = *(const f16x8*)(Al + fh);                                       \
    }
#define LOAD_B(T, BH, BL)                                                        \
    _Pragma("unroll")                                                            \
    for (int ni = 0; ni < 4; ++ni) {                                             \
        size_t o = ((size_t)((c0 + ni) * 8 + (T)) * 64 + lane) * 8;              \
        BH[ni] = *(const f16x8*)(Whp + o);                                       \
        BL[ni] = *(const f16x8*)(Wlp + o);                                       \
    }
#define DO_MFMA(AH, AL, BH, BL)                                                  \
    _Pragma("unroll")                                                            \
    for (int mi = 0; mi < 2; ++mi)                                               \
        _Pragma("unroll")                                                        \
        for (int ni = 0; ni < 4; ++ni) {                                         \
            acc[mi][ni] = __builtin_amdgcn_mfma_f32_16x16x32_f16(AH[mi], BH[ni], acc[mi][ni], 0, 0, 0); \
            acc[mi][ni] = __builtin_amdgcn_mfma_f32_16x16x32_f16(AL[mi], BH[ni], acc[mi][ni], 0, 0, 0); \
            acc[mi][ni] = __builtin_amdgcn_mfma_f32_16x16x32_f16(AH[mi], BL[ni], acc[mi][ni], 0, 0, 0); \
        }

template<int KP, bool FUSE>
__global__ __launch_bounds__(256, 2) void gemm_pipe(const ushort* __restrict__ Ah,
                                                    const ushort* __restrict__ Al,
                                                    const ushort* __restrict__ Whp,
                                                    const ushort* __restrict__ Wlp,
                                                    const float* __restrict__ b,
                                                    void* __restrict__ outv,
                                                    const float* __restrict__ fcw,
                                                    const float* __restrict__ nrm) {
    constexpr int NT = KP / 32;
    constexpr int NWG = (MPAD / 64) * 2;   // 1252 tiles
    constexpr int QD = NWG >> 3, RR = NWG & 7;   // 156, 4
    int q = blockIdx.x;
    int xcd = q & 7, orig = q >> 3;
    int tile = (xcd < RR ? xcd * (QD + 1) : RR * (QD + 1) + (xcd - RR) * QD) + orig;
    int m0 = (tile >> 1) * 64;
    int n0 = (tile & 1) * 128;

    int tid  = threadIdx.x;
    int wave = tid >> 6, lane = tid & 63;
    int wm = wave >> 1, wn = wave & 1;
    int lr = lane & 15, quad = lane >> 4;
    int c0 = (n0 + wn * 64) >> 4;          // first 16-col tile index

    f32x4 acc[2][4];
#pragma unroll
    for (int mi = 0; mi < 2; ++mi)
#pragma unroll
        for (int ni = 0; ni < 4; ++ni) acc[mi][ni] = {0.f, 0.f, 0.f, 0.f};

    f16x8 a0h[2], a0l[2], b0h[4], b0l[4];
    f16x8 a1h[2], a1l[2], b1h[4], b1l[4];
    LOAD_A(0, a0h, a0l)
    LOAD_B(0, b0h, b0l)
#pragma unroll
    for (int t = 0; t < NT; ++t) {
        if (t & 1) {
            if (t + 1 < NT) { LOAD_A(t + 1, a0h, a0l) LOAD_B(t + 1, b0h, b0l) }
            DO_MFMA(a1h, a1l, b1h, b1l)
        } else {
            if (t + 1 < NT) { LOAD_A(t + 1, a1h, a1l) LOAD_B(t + 1, b1h, b1l) }
            DO_MFMA(a0h, a0l, b0h, b0l)
        }
    }

    if (FUSE) {
        float* out = (float*)outv;
#pragma unroll
        for (int mi = 0; mi < 2; ++mi) {
#pragma unroll
            for (int i = 0; i < 4; ++i) {
                float p = 0.f;
#pragma unroll
                for (int ni = 0; ni < 4; ++ni) {
                    int c = n0 + wn * 64 + ni * 16 + lr;
                    if (c < 246)
                        p += fmaxf(acc[mi][ni][i] + b[c], 0.f) * fcw[c];
                }
#pragma unroll
                for (int off = 8; off > 0; off >>= 1)
                    p += __shfl_down(p, off, 16);
                int m = m0 + wm * 32 + mi * 16 + quad * 4 + i;
                if (lr == 0 && m < NN * SS)
                    atomicAdd(&out[m >> 1], 0.5f * p);
            }
        }
    } else {
        float* outF = (float*)outv;    // fp32 [M][256]; cols>=246 get 0 (acc=0, bj=0)
#pragma unroll
        for (int ni = 0; ni < 4; ++ni) {
            int c = n0 + wn * 64 + ni * 16 + lr;
            float bj = (c < 246) ? b[c] : 0.f;
#pragma unroll
            for (int mi = 0; mi < 2; ++mi)
#pragma unroll
                for (int i = 0; i < 4; ++i) {
                    int m = m0 + wm * 32 + mi * 16 + quad * 4 + i;
                    if (m < NN * SS) {
                        float no = nrm[m >> 1];
                        outF[(size_t)m * 256 + c] = fmaxf(acc[mi][ni][i] + bj, 0.f) * no;
                    }
                }
        }
    }
}

extern "C" void kernel_launch(void* const* d_in, const int* in_sizes, int n_in,
                              void* d_out, int out_size, void* d_ws, size_t ws_size,
                              hipStream_t stream) {
    const float* feat = (const float*)d_in[0];
    const int*   src  = (const int*)d_in[1];
    const int*   dst  = (const int*)d_in[2];
    const float* W0   = (const float*)d_in[3];
    const float* b0   = (const float*)d_in[4];
    const float* W1   = (const float*)d_in[5];
    const float* b1   = (const float*)d_in[6];
    const float* W2   = (const float*)d_in[7];
    const float* b2   = (const float*)d_in[8];
    const float* fcw  = (const float*)d_in[9];
    const float* fcb  = (const float*)d_in[10];
    float* out = (float*)d_out;

    char* ws = (char*)d_ws;
    size_t off = 0;
    auto alloc = [&](size_t bytes) {
        void* p = ws + off;
        off = (off + bytes + 255) & ~(size_t)255;
        return p;
    };
    int*    deg_out_i = (int*)alloc((2 * NN + 64) * sizeof(int));
    int*    deg_in_i  = deg_out_i + NN;
    int*    counter   = deg_out_i + 2 * NN;
    int*    row_start = (int*)alloc(NN * sizeof(int));
    int*    cursor    = (int*)alloc(NN * sizeof(int));
    ushort* sorted    = (ushort*)alloc((NE + 3 * NN + 16) * sizeof(ushort));
    float*  norm_out  = (float*)alloc((NN + 1) * sizeof(float));   // [NN] = 0 (pad)
    float*  norm_in   = (float*)alloc(NN * sizeof(float));
    ushort* Wh0 = (ushort*)alloc(256 * 256 * sizeof(ushort));
    ushort* Wl0 = (ushort*)alloc(256 * 256 * sizeof(ushort));
    ushort* Wh1 = (ushort*)alloc(256 * 256 * sizeof(ushort));
    ushort* Wl1 = (ushort*)alloc(256 * 256 * sizeof(ushort));
    ushort* Wh2 = (ushort*)alloc(256 * 256 * sizeof(ushort));
    ushort* Wl2 = (ushort*)alloc(256 * 256 * sizeof(ushort));
    ushort* Ahb = (ushort*)alloc((size_t)MPAD * 256 * sizeof(ushort));  // split A hi (K-tiled)
    ushort* Alb = (ushort*)alloc((size_t)MPAD * 256 * sizeof(ushort));  // split A lo (K-tiled)
    float*  bufH = (float*)alloc(((size_t)NN * SS * 256 + 512) * sizeof(float)); // +zero pad row

    hipMemsetAsync(deg_out_i, 0, (2 * NN + 1) * sizeof(int), stream);

    // K1: all independent setup (degree + W-split + init_out + pad zeroing)
    setup_kernel<<<2114, 256, 0, stream>>>(src, dst, deg_out_i, deg_in_i,
                                           W0, W1, W2, Wh0, Wl0, Wh1, Wl1, Wh2, Wl2,
                                           out, fcb, norm_out, Ahb, Alb, bufH);
    // K2: CSR ranges + norms (needs degree)
    alloc_kernel<<<(NN + 255) / 256, 256, 0, stream>>>(deg_out_i, deg_in_i, norm_out, norm_in,
                                                       row_start, cursor, counter);
    // K3: scatter + pad_fill (needs alloc)
    scatter_pad<<<1250 + (NN + 255) / 256, 256, 0, stream>>>(src, dst, cursor, sorted,
                                                             row_start, deg_in_i);

    const int NB8 = (NN + 7) / 8;             // 2500 node groups (8 nodes/block)
    const int GG  = (MPAD / 64) * 2;          // 1252 swizzled tiles

    // Layer 0: feat [N][2*128] -> agg (norm gathers, row clamp) -> gemm(*norm_out) -> bufH
    aggregate4<64, 4, true><<<NB8 * 4, 128, 0, stream>>>(feat, row_start, deg_in_i, sorted,
                                                         norm_out, norm_in, Ahb, Alb);
    gemm_pipe<FIN, false><<<GG, 256, 0, stream>>>(Ahb, Alb, Wh0, Wl0, b0, bufH, fcw, norm_out);

    // Layer 1: bufH (pre-scaled by norm_out) -> pure-sum agg -> gemm(*norm_out) -> bufH
    aggregate4<128, 8, false><<<NB8 * 8, 128, 0, stream>>>(bufH, row_start, deg_in_i, sorted,
                                                           norm_out, norm_in, Ahb, Alb);
    gemm_pipe<256, false><<<GG, 256, 0, stream>>>(Ahb, Alb, Wh1, Wl1, b1, bufH, fcw, norm_out);

    // Layer 2: bufH -> pure-sum agg -> fused gemm -> out (atomicAdd; out pre-set to fcb)
    aggregate4<128, 8, false><<<NB8 * 8, 128, 0, stream>>>(bufH, row_start, deg_in_i, sorted,
                                                           norm_out, norm_in, Ahb, Alb);
    gemm_pipe<256, true><<<GG, 256, 0, stream>>>(Ahb, Alb, Wh2, Wl2, b2, out, fcw, norm_out);
}